// Round 16
// baseline (452.216 us; speedup 1.0000x reference)
//
#include <hip/hip_runtime.h>

typedef _Float16 f16;
typedef __fp16 h16x2 __attribute__((ext_vector_type(2)));   // cvt_pkrtz result type
typedef _Float16 f16x4 __attribute__((ext_vector_type(4)));
typedef _Float16 f16x8 __attribute__((ext_vector_type(8)));
typedef float f32x4 __attribute__((ext_vector_type(4)));

// B=64, T=240, J=22, D=128, H=8, hd=16; rows = 337920 = 7680 groups * 44
#define N_ROWS   337920
#define RG       44
#define NGROUPS  7680
#define QKV_ROWB  512
#define LDS_BYTES (48 * QKV_ROWB)              // 24576 ONLY (Q/K + y) -> 5-6 WG/CU
#define WQKV_F16  49152
#define WOUT_F16  16384
#define MASK_OFF  ((WQKV_F16 + WOUT_F16) * 2)  // 131072
#define WS_NEEDED (MASK_OFF + 4096)
#define SCQ 0.3606737602222409f                // 0.25 * log2(e): exp2 softmax

__device__ __forceinline__ uint32_t swz(int row, int bytecol) {
  return (uint32_t)((row * QKV_ROWB + bytecol) ^ ((row & 7) << 4));
}
__device__ __forceinline__ f16x8 pack8z(float4 a, float4 b) {
  h16x2 p0 = __builtin_amdgcn_cvt_pkrtz(a.x, a.y);
  h16x2 p1 = __builtin_amdgcn_cvt_pkrtz(a.z, a.w);
  h16x2 p2 = __builtin_amdgcn_cvt_pkrtz(b.x, b.y);
  h16x2 p3 = __builtin_amdgcn_cvt_pkrtz(b.z, b.w);
  f16x8 r;
  r[0]=p0[0]; r[1]=p0[1]; r[2]=p1[0]; r[3]=p1[1];
  r[4]=p2[0]; r[5]=p2[1]; r[6]=p3[0]; r[7]=p3[1];
  return r;
}
__device__ __forceinline__ f16x4 pack4z(float a, float b, float c, float d) {
  h16x2 p0 = __builtin_amdgcn_cvt_pkrtz(a, b);
  h16x2 p1 = __builtin_amdgcn_cvt_pkrtz(c, d);
  f16x4 r;
  r[0]=p0[0]; r[1]=p0[1]; r[2]=p1[0]; r[3]=p1[1];
  return r;
}

__global__ void prep(const float* __restrict__ wqkv, const float* __restrict__ wout,
                     const int* __restrict__ adj, char* __restrict__ ws) {
  f16* w16 = (f16*)ws;
  int b = blockIdx.x;
  if (b < 64) {                                     // weights fp32 -> f16 (RTN)
    int i4 = (b * 256 + threadIdx.x) * 4;
    const float* src = (i4 < WQKV_F16) ? (wqkv + i4) : (wout + (i4 - WQKV_F16));
    float4 v = *(const float4*)src;
    f16x4 h;
    h[0]=(f16)v.x; h[1]=(f16)v.y; h[2]=(f16)v.z; h[3]=(f16)v.w;
    *(f16x4*)(w16 + i4) = h;
  } else {                                          // per-lane additive mask table
    int t = threadIdx.x;
    int qt = t >> 7, jt = (t >> 6) & 1, l = t & 63;
    int g = l >> 4, r16 = l & 15;
    f32x4 m;
    #pragma unroll
    for (int r = 0; r < 4; r++) {
      int q = qt * 16 + r16, j = jt * 16 + 4 * g + r;
      float v = -1e30f;
      if (j < 22) v = (q >= 22 || adj[q * 22 + j] > 0) ? 0.0f : -1e30f;
      m[r] = v;
    }
    *(f32x4*)(ws + MASK_OFF + t * 16) = m;
  }
}

// R15 = R13 structure, but V is computed IN phase 2 by its consumer wave
// (global->reg, no LDS, no barrier dep) -> vT buffer deleted, LDS 40960->24576.
template <int F16M>
__global__ __launch_bounds__(256, 5)
void mga_fused(const float* __restrict__ x, const int* __restrict__ adj,
               const float* __restrict__ bqkv, const float* __restrict__ bout,
               const char* __restrict__ ws, const float* __restrict__ wqkv32,
               const float* __restrict__ wout32,
               float* __restrict__ out) {
  __shared__ __align__(16) char smem[LDS_BYTES];
  const int tid = threadIdx.x;
  const int wv = tid >> 6;
  const int l = tid & 63;
  const int g = l >> 4;
  const int r16 = l & 15;
  const long g0 = (long)blockIdx.x * RG;
  const f16* w16 = (const f16*)ws;
  const f16* w16o = w16 + WQKV_F16;
  const int t = wv >> 1;                    // phase-2 token of this wave
  const int hbase = 4 * (wv & 1);           // phase-2 head-half

  // ============ x fragments ============
  // xf[3]: the group's 44 rows (Q/K A-frags). xfv[2]: token-padded rows for V.
  f16x8 xf[3][4];
  #pragma unroll
  for (int mt = 0; mt < 3; mt++) {
    long rowg = g0 + mt * 16 + r16;
    if (rowg > (long)N_ROWS - 1) rowg = N_ROWS - 1;
    const float* xp = x + rowg * 128 + g * 8;
    #pragma unroll
    for (int ks = 0; ks < 4; ks++)
      xf[mt][ks] = pack8z(*(const float4*)(xp + ks * 32),
                          *(const float4*)(xp + ks * 32 + 4));
  }
  f16x8 xfv[2][4];
  {
    const long tb = g0 + 22 * t;
    int rv1 = 16 + r16; if (rv1 > 21) rv1 = 21;     // clamp inside token (masked)
    const float* xv0 = x + (tb + r16) * 128 + g * 8;
    const float* xv1 = x + (tb + rv1) * 128 + g * 8;
    #pragma unroll
    for (int ks = 0; ks < 4; ks++) {
      xfv[0][ks] = pack8z(*(const float4*)(xv0 + ks * 32), *(const float4*)(xv0 + ks * 32 + 4));
      xfv[1][ks] = pack8z(*(const float4*)(xv1 + ks * 32), *(const float4*)(xv1 + ks * 32 + 4));
    }
  }

  // ============ Phase 1: Q/K projection ONLY (4 tiles/wave, W dbuf) ============
  f16x8 wcur[4], wnxt[4];
  {
    int wrow = wv * 16 + r16;
    #pragma unroll
    for (int ks = 0; ks < 4; ks++) {
      int off = wrow * 128 + ks * 32 + g * 8;
      if (F16M) wcur[ks] = *(const f16x8*)(w16 + off);
      else      wcur[ks] = pack8z(*(const float4*)(wqkv32 + off),
                                  *(const float4*)(wqkv32 + off + 4));
    }
  }
  #pragma unroll 1                                   // ROLLED: 4 iterations (Q,Q,K,K)
  for (int i = 0; i < 4; i++) {
    int nt = wv + 4 * i;
    if (i < 3) {
      int wrow = (nt + 4) * 16 + r16;
      #pragma unroll
      for (int ks = 0; ks < 4; ks++) {
        int off = wrow * 128 + ks * 32 + g * 8;
        if (F16M) wnxt[ks] = *(const f16x8*)(w16 + off);
        else      wnxt[ks] = pack8z(*(const float4*)(wqkv32 + off),
                                    *(const float4*)(wqkv32 + off + 4));
      }
    }
    f32x4 bb = *(const f32x4*)(bqkv + nt * 16 + 4 * g);
    f32x4 acc[3] = {bb, bb, bb};        // bias as C-init
    #pragma unroll
    for (int ks = 0; ks < 4; ks++) {
      acc[0] = __builtin_amdgcn_mfma_f32_16x16x32_f16(wcur[ks], xf[0][ks], acc[0], 0,0,0);
      acc[1] = __builtin_amdgcn_mfma_f32_16x16x32_f16(wcur[ks], xf[1][ks], acc[1], 0,0,0);
      acc[2] = __builtin_amdgcn_mfma_f32_16x16x32_f16(wcur[ks], xf[2][ks], acc[2], 0,0,0);
    }
    float sc = (nt < 8) ? SCQ : 1.0f;   // Q: fold 0.25*log2e (exp2 softmax)
    int col = nt * 16 + 4 * g;
    #pragma unroll
    for (int mt = 0; mt < 3; mt++) {
      f16x4 h4 = pack4z(acc[mt][0] * sc, acc[mt][1] * sc,
                        acc[mt][2] * sc, acc[mt][3] * sc);
      *(f16x4*)(smem + swz(mt * 16 + r16, col * 2)) = h4;
    }
    #pragma unroll
    for (int ks = 0; ks < 4; ks++) wcur[ks] = wnxt[ks];
  }

  // mask regs: coalesced table loads (fallback path computes from adj)
  f32x4 mq[2][2];
  if (F16M) {
    #pragma unroll
    for (int qt = 0; qt < 2; qt++)
      #pragma unroll
      for (int jt = 0; jt < 2; jt++)
        mq[qt][jt] = *(const f32x4*)(ws + MASK_OFF + ((qt * 2 + jt) * 64 + l) * 16);
  } else {
    #pragma unroll
    for (int qt = 0; qt < 2; qt++)
      #pragma unroll
      for (int jt = 0; jt < 2; jt++)
        #pragma unroll
        for (int r = 0; r < 4; r++) {
          int q = qt * 16 + r16, j = jt * 16 + 4 * g + r;
          float m = -1e30f;
          if (j < 22) m = (q >= 22 || adj[q * 22 + j] > 0) ? 0.0f : -1e30f;
          mq[qt][jt][r] = m;
        }
  }

  __syncthreads();

  // ============ Phase 2: attention; V computed INLINE per head (no LDS) ========
  {
    const int rbase = 22 * t;
    const int rowk0 = rbase + r16;
    int rk1 = rbase + 16 + r16; if (rk1 > 47) rk1 = 47;   // clamped (finite, masked)
    const int rowk1 = rk1;
    #pragma unroll 1                                 // ROLLED: 4 head iterations
    for (int hi = 0; hi < 4; hi++) {
      int h = hbase + hi;
      // --- V projection for this head: global->reg, acc IS the PV A-frag ---
      f16x8 wvf[4];
      #pragma unroll
      for (int ks = 0; ks < 4; ks++) {
        int off = (256 + h * 16 + r16) * 128 + ks * 32 + g * 8;
        if (F16M) wvf[ks] = *(const f16x8*)(w16 + off);
        else      wvf[ks] = pack8z(*(const float4*)(wqkv32 + off),
                                   *(const float4*)(wqkv32 + off + 4));
      }
      float bvs = bqkv[256 + h * 16 + r16];
      f32x4 bbv = {bvs, bvs, bvs, bvs};
      f32x4 aV0 = bbv, aV1 = bbv;
      #pragma unroll
      for (int ks = 0; ks < 4; ks++) {
        aV0 = __builtin_amdgcn_mfma_f32_16x16x32_f16(xfv[0][ks], wvf[ks], aV0, 0,0,0);
        aV1 = __builtin_amdgcn_mfma_f32_16x16x32_f16(xfv[1][ks], wvf[ks], aV1, 0,0,0);
      }
      f16x4 vf0 = pack4z(aV0[0], aV0[1], aV0[2], aV0[3]);
      f16x4 vf1 = pack4z(aV1[0], aV1[1], aV1[2], aV1[3]);

      // --- QK^T + softmax + PV ---
      f16x4 kf0 = *(const f16x4*)(smem + swz(rowk0, (128 + h * 16 + 4 * g) * 2));
      f16x4 kf1 = *(const f16x4*)(smem + swz(rowk1, (128 + h * 16 + 4 * g) * 2));
      #pragma unroll
      for (int qt = 0; qt < 2; qt++) {
        int rowq = qt ? rowk1 : rowk0;
        f16x4 qf = *(const f16x4*)(smem + swz(rowq, (h * 16 + 4 * g) * 2));
        f32x4 z = {0.f, 0.f, 0.f, 0.f};
        f32x4 s0 = __builtin_amdgcn_mfma_f32_16x16x16f16(kf0, qf, z, 0, 0, 0);
        f32x4 s1 = __builtin_amdgcn_mfma_f32_16x16x16f16(kf1, qf, z, 0, 0, 0);
        float p[8];
        #pragma unroll
        for (int r = 0; r < 4; r++) {
          p[r]     = __builtin_exp2f(s0[r] + mq[qt][0][r]);  // exp2(-1e30)==0 kills mask
          p[4 + r] = __builtin_exp2f(s1[r] + mq[qt][1][r]);
        }
        float sum = ((p[0] + p[1]) + (p[2] + p[3])) + ((p[4] + p[5]) + (p[6] + p[7]));
        sum += __shfl_xor(sum, 16, 64);
        sum += __shfl_xor(sum, 32, 64);             // hides under P-pack + PV MFMA
        f16x4 pb0 = pack4z(p[0], p[1], p[2], p[3]);
        f16x4 pb1 = pack4z(p[4], p[5], p[6], p[7]);
        f32x4 ya = __builtin_amdgcn_mfma_f32_16x16x16f16(vf0, pb0, z, 0, 0, 0);
        ya = __builtin_amdgcn_mfma_f32_16x16x16f16(vf1, pb1, ya, 0, 0, 0);
        float inv = __builtin_amdgcn_rcpf(sum);
        int q = qt * 16 + r16;
        if (q < 22) {                   // y overwrites dead Q slot (same head's dims)
          f16x4 yh = pack4z(ya[0] * inv, ya[1] * inv, ya[2] * inv, ya[3] * inv);
          *(f16x4*)(smem + swz(rbase + q, (h * 16 + 4 * g) * 2)) = yh;
        }
      }
    }
  }
  __syncthreads();

  // ============ Phase 3: out projection (bias via C-init) ============
  f16x8 wf3a[4], wf3b[4];
  #pragma unroll
  for (int ks = 0; ks < 4; ks++) {
    int offa = (2 * wv * 16 + r16) * 128 + ks * 32 + g * 8;
    int offb = ((2 * wv + 1) * 16 + r16) * 128 + ks * 32 + g * 8;
    if (F16M) {
      wf3a[ks] = *(const f16x8*)(w16o + offa);
      wf3b[ks] = *(const f16x8*)(w16o + offb);
    } else {
      wf3a[ks] = pack8z(*(const float4*)(wout32 + offa), *(const float4*)(wout32 + offa + 4));
      wf3b[ks] = pack8z(*(const float4*)(wout32 + offb), *(const float4*)(wout32 + offb + 4));
    }
  }
  f32x4 bva = *(const f32x4*)(bout + 2 * wv * 16 + 4 * g);
  f32x4 bvb = *(const f32x4*)(bout + (2 * wv + 1) * 16 + 4 * g);
  #pragma unroll 1                                   // ROLLED: 3 iterations
  for (int mt = 0; mt < 3; mt++) {
    f16x8 af[4];
    #pragma unroll
    for (int ks = 0; ks < 4; ks++)
      af[ks] = *(const f16x8*)(smem + swz(mt * 16 + r16, (ks * 32 + g * 8) * 2));
    int rowl = mt * 16 + r16;
    f32x4 acc0 = bva, acc1 = bvb;
    #pragma unroll
    for (int ks = 0; ks < 4; ks++) {
      acc0 = __builtin_amdgcn_mfma_f32_16x16x32_f16(wf3a[ks], af[ks], acc0, 0, 0, 0);
      acc1 = __builtin_amdgcn_mfma_f32_16x16x32_f16(wf3b[ks], af[ks], acc1, 0, 0, 0);
    }
    if (rowl < RG) {
      float4 oa, ob;
      oa.x = acc0[0]; oa.y = acc0[1]; oa.z = acc0[2]; oa.w = acc0[3];
      ob.x = acc1[0]; ob.y = acc1[1]; ob.z = acc1[2]; ob.w = acc1[3];
      *(float4*)(out + (g0 + rowl) * 128 + 2 * wv * 16 + 4 * g) = oa;
      *(float4*)(out + (g0 + rowl) * 128 + (2 * wv + 1) * 16 + 4 * g) = ob;
    }
  }
}

extern "C" void kernel_launch(void* const* d_in, const int* in_sizes, int n_in,
                              void* d_out, int out_size, void* d_ws, size_t ws_size,
                              hipStream_t stream) {
  const float* x    = (const float*)d_in[0];
  const int*   adj  = (const int*)d_in[1];
  const float* wqkv = (const float*)d_in[2];
  const float* bqkv = (const float*)d_in[3];
  const float* wout = (const float*)d_in[4];
  const float* bout = (const float*)d_in[5];
  float* o = (float*)d_out;

  int f16m = (d_ws != nullptr && ws_size >= (size_t)WS_NEEDED) ? 1 : 0;
  if (f16m) {
    prep<<<dim3(65), dim3(256), 0, stream>>>(wqkv, wout, adj, (char*)d_ws);
    mga_fused<1><<<dim3(NGROUPS), dim3(256), 0, stream>>>(
        x, adj, bqkv, bout, (const char*)d_ws, wqkv, wout, o);
  } else {
    mga_fused<0><<<dim3(NGROUPS), dim3(256), 0, stream>>>(
        x, adj, bqkv, bout, (const char*)d_ws, wqkv, wout, o);
  }
}

// Round 17
// 293.441 us; speedup vs baseline: 1.5411x; 1.5411x over previous
//
#include <hip/hip_runtime.h>

typedef _Float16 f16;
typedef __fp16 h16x2 __attribute__((ext_vector_type(2)));   // cvt_pkrtz result type
typedef _Float16 f16x4 __attribute__((ext_vector_type(4)));
typedef _Float16 f16x8 __attribute__((ext_vector_type(8)));
typedef float f32x4 __attribute__((ext_vector_type(4)));

// B=64, T=240, J=22, D=128, H=8, hd=16; rows = 337920 = 7680 groups * 44
#define N_ROWS   337920
#define RG       44
#define NGROUPS  7680
#define QKV_ROWB  512
#define LDS_BYTES (48 * QKV_ROWB)              // 24576 ONLY (Q/K + y)
#define WQKV_F16  49152
#define WOUT_F16  16384
#define MASK_OFF  ((WQKV_F16 + WOUT_F16) * 2)  // 131072
#define WS_NEEDED (MASK_OFF + 4096)
#define SCQ 0.3606737602222409f                // 0.25 * log2(e): exp2 softmax

__device__ __forceinline__ uint32_t swz(int row, int bytecol) {
  return (uint32_t)((row * QKV_ROWB + bytecol) ^ ((row & 7) << 4));
}
__device__ __forceinline__ f16x8 pack8z(float4 a, float4 b) {
  h16x2 p0 = __builtin_amdgcn_cvt_pkrtz(a.x, a.y);
  h16x2 p1 = __builtin_amdgcn_cvt_pkrtz(a.z, a.w);
  h16x2 p2 = __builtin_amdgcn_cvt_pkrtz(b.x, b.y);
  h16x2 p3 = __builtin_amdgcn_cvt_pkrtz(b.z, b.w);
  f16x8 r;
  r[0]=p0[0]; r[1]=p0[1]; r[2]=p1[0]; r[3]=p1[1];
  r[4]=p2[0]; r[5]=p2[1]; r[6]=p3[0]; r[7]=p3[1];
  return r;
}
__device__ __forceinline__ f16x4 pack4z(float a, float b, float c, float d) {
  h16x2 p0 = __builtin_amdgcn_cvt_pkrtz(a, b);
  h16x2 p1 = __builtin_amdgcn_cvt_pkrtz(c, d);
  f16x4 r;
  r[0]=p0[0]; r[1]=p0[1]; r[2]=p1[0]; r[3]=p1[1];
  return r;
}

__global__ void prep(const float* __restrict__ wqkv, const float* __restrict__ wout,
                     const int* __restrict__ adj, char* __restrict__ ws) {
  f16* w16 = (f16*)ws;
  int b = blockIdx.x;
  if (b < 64) {                                     // weights fp32 -> f16 (RTN)
    int i4 = (b * 256 + threadIdx.x) * 4;
    const float* src = (i4 < WQKV_F16) ? (wqkv + i4) : (wout + (i4 - WQKV_F16));
    float4 v = *(const float4*)src;
    f16x4 h;
    h[0]=(f16)v.x; h[1]=(f16)v.y; h[2]=(f16)v.z; h[3]=(f16)v.w;
    *(f16x4*)(w16 + i4) = h;
  } else {                                          // per-lane additive mask table
    int t = threadIdx.x;
    int qt = t >> 7, jt = (t >> 6) & 1, l = t & 63;
    int g = l >> 4, r16 = l & 15;
    f32x4 m;
    #pragma unroll
    for (int r = 0; r < 4; r++) {
      int q = qt * 16 + r16, j = jt * 16 + 4 * g + r;
      float v = -1e30f;
      if (j < 22) v = (q >= 22 || adj[q * 22 + j] > 0) ? 0.0f : -1e30f;
      m[r] = v;
    }
    *(f32x4*)(ws + MASK_OFF + t * 16) = m;
  }
}

// R16 = R15 structure (V inline in phase 2, no vT LDS) with launch_bounds(256,2):
// the ONLY change vs R15 — isolates the spill cause (VGPR starvation).
template <int F16M>
__global__ __launch_bounds__(256, 2)
void mga_fused(const float* __restrict__ x, const int* __restrict__ adj,
               const float* __restrict__ bqkv, const float* __restrict__ bout,
               const char* __restrict__ ws, const float* __restrict__ wqkv32,
               const float* __restrict__ wout32,
               float* __restrict__ out) {
  __shared__ __align__(16) char smem[LDS_BYTES];
  const int tid = threadIdx.x;
  const int wv = tid >> 6;
  const int l = tid & 63;
  const int g = l >> 4;
  const int r16 = l & 15;
  const long g0 = (long)blockIdx.x * RG;
  const f16* w16 = (const f16*)ws;
  const f16* w16o = w16 + WQKV_F16;
  const int t = wv >> 1;                    // phase-2 token of this wave
  const int hbase = 4 * (wv & 1);           // phase-2 head-half

  // ============ x fragments ============
  f16x8 xf[3][4];
  #pragma unroll
  for (int mt = 0; mt < 3; mt++) {
    long rowg = g0 + mt * 16 + r16;
    if (rowg > (long)N_ROWS - 1) rowg = N_ROWS - 1;
    const float* xp = x + rowg * 128 + g * 8;
    #pragma unroll
    for (int ks = 0; ks < 4; ks++)
      xf[mt][ks] = pack8z(*(const float4*)(xp + ks * 32),
                          *(const float4*)(xp + ks * 32 + 4));
  }
  f16x8 xfv[2][4];
  {
    const long tb = g0 + 22 * t;
    int rv1 = 16 + r16; if (rv1 > 21) rv1 = 21;     // clamp inside token (masked)
    const float* xv0 = x + (tb + r16) * 128 + g * 8;
    const float* xv1 = x + (tb + rv1) * 128 + g * 8;
    #pragma unroll
    for (int ks = 0; ks < 4; ks++) {
      xfv[0][ks] = pack8z(*(const float4*)(xv0 + ks * 32), *(const float4*)(xv0 + ks * 32 + 4));
      xfv[1][ks] = pack8z(*(const float4*)(xv1 + ks * 32), *(const float4*)(xv1 + ks * 32 + 4));
    }
  }

  // ============ Phase 1: Q/K projection ONLY (4 tiles/wave, W dbuf) ============
  f16x8 wcur[4], wnxt[4];
  {
    int wrow = wv * 16 + r16;
    #pragma unroll
    for (int ks = 0; ks < 4; ks++) {
      int off = wrow * 128 + ks * 32 + g * 8;
      if (F16M) wcur[ks] = *(const f16x8*)(w16 + off);
      else      wcur[ks] = pack8z(*(const float4*)(wqkv32 + off),
                                  *(const float4*)(wqkv32 + off + 4));
    }
  }
  #pragma unroll 1                                   // ROLLED: 4 iterations (Q,Q,K,K)
  for (int i = 0; i < 4; i++) {
    int nt = wv + 4 * i;
    if (i < 3) {
      int wrow = (nt + 4) * 16 + r16;
      #pragma unroll
      for (int ks = 0; ks < 4; ks++) {
        int off = wrow * 128 + ks * 32 + g * 8;
        if (F16M) wnxt[ks] = *(const f16x8*)(w16 + off);
        else      wnxt[ks] = pack8z(*(const float4*)(wqkv32 + off),
                                    *(const float4*)(wqkv32 + off + 4));
      }
    }
    f32x4 bb = *(const f32x4*)(bqkv + nt * 16 + 4 * g);
    f32x4 acc[3] = {bb, bb, bb};        // bias as C-init
    #pragma unroll
    for (int ks = 0; ks < 4; ks++) {
      acc[0] = __builtin_amdgcn_mfma_f32_16x16x32_f16(wcur[ks], xf[0][ks], acc[0], 0,0,0);
      acc[1] = __builtin_amdgcn_mfma_f32_16x16x32_f16(wcur[ks], xf[1][ks], acc[1], 0,0,0);
      acc[2] = __builtin_amdgcn_mfma_f32_16x16x32_f16(wcur[ks], xf[2][ks], acc[2], 0,0,0);
    }
    float sc = (nt < 8) ? SCQ : 1.0f;   // Q: fold 0.25*log2e (exp2 softmax)
    int col = nt * 16 + 4 * g;
    #pragma unroll
    for (int mt = 0; mt < 3; mt++) {
      f16x4 h4 = pack4z(acc[mt][0] * sc, acc[mt][1] * sc,
                        acc[mt][2] * sc, acc[mt][3] * sc);
      *(f16x4*)(smem + swz(mt * 16 + r16, col * 2)) = h4;
    }
    #pragma unroll
    for (int ks = 0; ks < 4; ks++) wcur[ks] = wnxt[ks];
  }

  // mask regs: coalesced table loads (fallback path computes from adj)
  f32x4 mq[2][2];
  if (F16M) {
    #pragma unroll
    for (int qt = 0; qt < 2; qt++)
      #pragma unroll
      for (int jt = 0; jt < 2; jt++)
        mq[qt][jt] = *(const f32x4*)(ws + MASK_OFF + ((qt * 2 + jt) * 64 + l) * 16);
  } else {
    #pragma unroll
    for (int qt = 0; qt < 2; qt++)
      #pragma unroll
      for (int jt = 0; jt < 2; jt++)
        #pragma unroll
        for (int r = 0; r < 4; r++) {
          int q = qt * 16 + r16, j = jt * 16 + 4 * g + r;
          float m = -1e30f;
          if (j < 22) m = (q >= 22 || adj[q * 22 + j] > 0) ? 0.0f : -1e30f;
          mq[qt][jt][r] = m;
        }
  }

  __syncthreads();

  // ============ Phase 2: attention; V computed INLINE per head (no LDS) ========
  {
    const int rbase = 22 * t;
    const int rowk0 = rbase + r16;
    int rk1 = rbase + 16 + r16; if (rk1 > 47) rk1 = 47;   // clamped (finite, masked)
    const int rowk1 = rk1;
    #pragma unroll 1                                 // ROLLED: 4 head iterations
    for (int hi = 0; hi < 4; hi++) {
      int h = hbase + hi;
      // --- V projection for this head: global->reg, acc IS the PV A-frag ---
      f16x8 wvf[4];
      #pragma unroll
      for (int ks = 0; ks < 4; ks++) {
        int off = (256 + h * 16 + r16) * 128 + ks * 32 + g * 8;
        if (F16M) wvf[ks] = *(const f16x8*)(w16 + off);
        else      wvf[ks] = pack8z(*(const float4*)(wqkv32 + off),
                                   *(const float4*)(wqkv32 + off + 4));
      }
      float bvs = bqkv[256 + h * 16 + r16];
      f32x4 bbv = {bvs, bvs, bvs, bvs};
      f32x4 aV0 = bbv, aV1 = bbv;
      #pragma unroll
      for (int ks = 0; ks < 4; ks++) {
        aV0 = __builtin_amdgcn_mfma_f32_16x16x32_f16(xfv[0][ks], wvf[ks], aV0, 0,0,0);
        aV1 = __builtin_amdgcn_mfma_f32_16x16x32_f16(xfv[1][ks], wvf[ks], aV1, 0,0,0);
      }
      f16x4 vf0 = pack4z(aV0[0], aV0[1], aV0[2], aV0[3]);
      f16x4 vf1 = pack4z(aV1[0], aV1[1], aV1[2], aV1[3]);

      // --- QK^T + softmax + PV ---
      f16x4 kf0 = *(const f16x4*)(smem + swz(rowk0, (128 + h * 16 + 4 * g) * 2));
      f16x4 kf1 = *(const f16x4*)(smem + swz(rowk1, (128 + h * 16 + 4 * g) * 2));
      #pragma unroll
      for (int qt = 0; qt < 2; qt++) {
        int rowq = qt ? rowk1 : rowk0;
        f16x4 qf = *(const f16x4*)(smem + swz(rowq, (h * 16 + 4 * g) * 2));
        f32x4 z = {0.f, 0.f, 0.f, 0.f};
        f32x4 s0 = __builtin_amdgcn_mfma_f32_16x16x16f16(kf0, qf, z, 0, 0, 0);
        f32x4 s1 = __builtin_amdgcn_mfma_f32_16x16x16f16(kf1, qf, z, 0, 0, 0);
        float p[8];
        #pragma unroll
        for (int r = 0; r < 4; r++) {
          p[r]     = __builtin_exp2f(s0[r] + mq[qt][0][r]);  // exp2(-1e30)==0 kills mask
          p[4 + r] = __builtin_exp2f(s1[r] + mq[qt][1][r]);
        }
        float sum = ((p[0] + p[1]) + (p[2] + p[3])) + ((p[4] + p[5]) + (p[6] + p[7]));
        sum += __shfl_xor(sum, 16, 64);
        sum += __shfl_xor(sum, 32, 64);             // hides under P-pack + PV MFMA
        f16x4 pb0 = pack4z(p[0], p[1], p[2], p[3]);
        f16x4 pb1 = pack4z(p[4], p[5], p[6], p[7]);
        f32x4 ya = __builtin_amdgcn_mfma_f32_16x16x16f16(vf0, pb0, z, 0, 0, 0);
        ya = __builtin_amdgcn_mfma_f32_16x16x16f16(vf1, pb1, ya, 0, 0, 0);
        float inv = __builtin_amdgcn_rcpf(sum);
        int q = qt * 16 + r16;
        if (q < 22) {                   // y overwrites dead Q slot (same head's dims)
          f16x4 yh = pack4z(ya[0] * inv, ya[1] * inv, ya[2] * inv, ya[3] * inv);
          *(f16x4*)(smem + swz(rbase + q, (h * 16 + 4 * g) * 2)) = yh;
        }
      }
    }
  }
  __syncthreads();

  // ============ Phase 3: out projection (bias via C-init) ============
  f16x8 wf3a[4], wf3b[4];
  #pragma unroll
  for (int ks = 0; ks < 4; ks++) {
    int offa = (2 * wv * 16 + r16) * 128 + ks * 32 + g * 8;
    int offb = ((2 * wv + 1) * 16 + r16) * 128 + ks * 32 + g * 8;
    if (F16M) {
      wf3a[ks] = *(const f16x8*)(w16o + offa);
      wf3b[ks] = *(const f16x8*)(w16o + offb);
    } else {
      wf3a[ks] = pack8z(*(const float4*)(wout32 + offa), *(const float4*)(wout32 + offa + 4));
      wf3b[ks] = pack8z(*(const float4*)(wout32 + offb), *(const float4*)(wout32 + offb + 4));
    }
  }
  f32x4 bva = *(const f32x4*)(bout + 2 * wv * 16 + 4 * g);
  f32x4 bvb = *(const f32x4*)(bout + (2 * wv + 1) * 16 + 4 * g);
  #pragma unroll 1                                   // ROLLED: 3 iterations
  for (int mt = 0; mt < 3; mt++) {
    f16x8 af[4];
    #pragma unroll
    for (int ks = 0; ks < 4; ks++)
      af[ks] = *(const f16x8*)(smem + swz(mt * 16 + r16, (ks * 32 + g * 8) * 2));
    int rowl = mt * 16 + r16;
    f32x4 acc0 = bva, acc1 = bvb;
    #pragma unroll
    for (int ks = 0; ks < 4; ks++) {
      acc0 = __builtin_amdgcn_mfma_f32_16x16x32_f16(wf3a[ks], af[ks], acc0, 0, 0, 0);
      acc1 = __builtin_amdgcn_mfma_f32_16x16x32_f16(wf3b[ks], af[ks], acc1, 0, 0, 0);
    }
    if (rowl < RG) {
      float4 oa, ob;
      oa.x = acc0[0]; oa.y = acc0[1]; oa.z = acc0[2]; oa.w = acc0[3];
      ob.x = acc1[0]; ob.y = acc1[1]; ob.z = acc1[2]; ob.w = acc1[3];
      *(float4*)(out + (g0 + rowl) * 128 + 2 * wv * 16 + 4 * g) = oa;
      *(float4*)(out + (g0 + rowl) * 128 + (2 * wv + 1) * 16 + 4 * g) = ob;
    }
  }
}

extern "C" void kernel_launch(void* const* d_in, const int* in_sizes, int n_in,
                              void* d_out, int out_size, void* d_ws, size_t ws_size,
                              hipStream_t stream) {
  const float* x    = (const float*)d_in[0];
  const int*   adj  = (const int*)d_in[1];
  const float* wqkv = (const float*)d_in[2];
  const float* bqkv = (const float*)d_in[3];
  const float* wout = (const float*)d_in[4];
  const float* bout = (const float*)d_in[5];
  float* o = (float*)d_out;

  int f16m = (d_ws != nullptr && ws_size >= (size_t)WS_NEEDED) ? 1 : 0;
  if (f16m) {
    prep<<<dim3(65), dim3(256), 0, stream>>>(wqkv, wout, adj, (char*)d_ws);
    mga_fused<1><<<dim3(NGROUPS), dim3(256), 0, stream>>>(
        x, adj, bqkv, bout, (const char*)d_ws, wqkv, wout, o);
  } else {
    mga_fused<0><<<dim3(NGROUPS), dim3(256), 0, stream>>>(
        x, adj, bqkv, bout, (const char*)d_ws, wqkv, wout, o);
  }
}

// Round 18
// 222.260 us; speedup vs baseline: 2.0346x; 1.3203x over previous
//
#include <hip/hip_runtime.h>

typedef _Float16 f16;
typedef __fp16 h16x2 __attribute__((ext_vector_type(2)));   // cvt_pkrtz result type
typedef _Float16 f16x4 __attribute__((ext_vector_type(4)));
typedef _Float16 f16x8 __attribute__((ext_vector_type(8)));
typedef float f32x4 __attribute__((ext_vector_type(4)));

// B=64, T=240, J=22, D=128, H=8, hd=16; rows = 337920 = 7680 groups * 44
#define N_ROWS   337920
#define RG       44
#define NGROUPS  7680
#define QKV_ROWB  512
#define QKV_BYTES (48 * QKV_ROWB)              // 24576
#define VT_OFF    QKV_BYTES
#define LDS_BYTES (QKV_BYTES + 128 * 64 * 2)   // 40960 -> 4 WG/CU by LDS
#define WQKV_F16  49152
#define WOUT_F16  16384
#define MASK_OFF  ((WQKV_F16 + WOUT_F16) * 2)  // 131072
#define WS_NEEDED (MASK_OFF + 4096)
#define SCQ 0.3606737602222409f                // 0.25 * log2(e): exp2 softmax

__device__ __forceinline__ uint32_t swz(int row, int bytecol) {
  return (uint32_t)((row * QKV_ROWB + bytecol) ^ ((row & 7) << 4));
}
__device__ __forceinline__ uint32_t vswz(int d, int col) {
  return (uint32_t)(VT_OFF + ((d * 128 + col * 2) ^ ((d & 15) << 3)));
}
__device__ __forceinline__ f16x8 pack8z(float4 a, float4 b) {
  h16x2 p0 = __builtin_amdgcn_cvt_pkrtz(a.x, a.y);
  h16x2 p1 = __builtin_amdgcn_cvt_pkrtz(a.z, a.w);
  h16x2 p2 = __builtin_amdgcn_cvt_pkrtz(b.x, b.y);
  h16x2 p3 = __builtin_amdgcn_cvt_pkrtz(b.z, b.w);
  f16x8 r;
  r[0]=p0[0]; r[1]=p0[1]; r[2]=p1[0]; r[3]=p1[1];
  r[4]=p2[0]; r[5]=p2[1]; r[6]=p3[0]; r[7]=p3[1];
  return r;
}
__device__ __forceinline__ f16x4 pack4z(float a, float b, float c, float d) {
  h16x2 p0 = __builtin_amdgcn_cvt_pkrtz(a, b);
  h16x2 p1 = __builtin_amdgcn_cvt_pkrtz(c, d);
  f16x4 r;
  r[0]=p0[0]; r[1]=p0[1]; r[2]=p1[0]; r[3]=p1[1];
  return r;
}

__global__ void prep(const float* __restrict__ wqkv, const float* __restrict__ wout,
                     const int* __restrict__ adj, char* __restrict__ ws) {
  f16* w16 = (f16*)ws;
  int b = blockIdx.x;
  if (b < 64) {                                     // weights fp32 -> f16 (RTN)
    int i4 = (b * 256 + threadIdx.x) * 4;
    const float* src = (i4 < WQKV_F16) ? (wqkv + i4) : (wout + (i4 - WQKV_F16));
    float4 v = *(const float4*)src;
    f16x4 h;
    h[0]=(f16)v.x; h[1]=(f16)v.y; h[2]=(f16)v.z; h[3]=(f16)v.w;
    *(f16x4*)(w16 + i4) = h;
  } else {                                          // per-lane additive mask table
    int t = threadIdx.x;
    int qt = t >> 7, jt = (t >> 6) & 1, l = t & 63;
    int g = l >> 4, r16 = l & 15;
    f32x4 m;
    #pragma unroll
    for (int r = 0; r < 4; r++) {
      int q = qt * 16 + r16, j = jt * 16 + 4 * g + r;
      float v = -1e30f;
      if (j < 22) v = (q >= 22 || adj[q * 22 + j] > 0) ? 0.0f : -1e30f;
      m[r] = v;
    }
    *(f32x4*)(ws + MASK_OFF + t * 16) = m;
  }
}

// R17 = R13 (best, 235 us steady) + s_setprio(1) around phase-2 compute (T5).
template <int F16M>
__global__ __launch_bounds__(256, 2)
void mga_fused(const float* __restrict__ x, const int* __restrict__ adj,
               const float* __restrict__ bqkv, const float* __restrict__ bout,
               const char* __restrict__ ws, const float* __restrict__ wqkv32,
               const float* __restrict__ wout32,
               float* __restrict__ out) {
  __shared__ __align__(16) char smem[LDS_BYTES];
  const int tid = threadIdx.x;
  const int wv = tid >> 6;
  const int l = tid & 63;
  const int g = l >> 4;
  const int r16 = l & 15;
  const long g0 = (long)blockIdx.x * RG;
  const f16* w16 = (const f16*)ws;
  const f16* w16o = w16 + WQKV_F16;

  // zero never-written vT cols (j>=22) of THIS WAVE's d-regions only (no barrier)
  {
    int d = 16 * wv + 64 * ((l >> 5) & 1) + (l & 15);
    int c0 = ((l >> 4) & 1) ? 54 : 22;
    #pragma unroll
    for (int i = 0; i < 5; i++)
      *(int*)(smem + vswz(d, c0 + 2 * i)) = 0;
  }

  // ============ Phase 1: QKV projection (W dbuf; bias via MFMA C-init) ============
  f16x8 xf[3][4];
  #pragma unroll
  for (int mt = 0; mt < 3; mt++) {
    long rowg = g0 + mt * 16 + r16;
    if (rowg > (long)N_ROWS - 1) rowg = N_ROWS - 1;
    const float* xp = x + rowg * 128 + g * 8;
    #pragma unroll
    for (int ks = 0; ks < 4; ks++)
      xf[mt][ks] = pack8z(*(const float4*)(xp + ks * 32),
                          *(const float4*)(xp + ks * 32 + 4));
  }

  f16x8 wcur[4], wnxt[4];
  {
    int wrow = wv * 16 + r16;
    #pragma unroll
    for (int ks = 0; ks < 4; ks++) {
      int off = wrow * 128 + ks * 32 + g * 8;
      if (F16M) wcur[ks] = *(const f16x8*)(w16 + off);
      else      wcur[ks] = pack8z(*(const float4*)(wqkv32 + off),
                                  *(const float4*)(wqkv32 + off + 4));
    }
  }
  #pragma unroll 1                                   // ROLLED: 6 iterations
  for (int i = 0; i < 6; i++) {
    int nt = wv + 4 * i;
    if (i < 5) {
      int wrow = (nt + 4) * 16 + r16;
      #pragma unroll
      for (int ks = 0; ks < 4; ks++) {
        int off = wrow * 128 + ks * 32 + g * 8;
        if (F16M) wnxt[ks] = *(const f16x8*)(w16 + off);
        else      wnxt[ks] = pack8z(*(const float4*)(wqkv32 + off),
                                    *(const float4*)(wqkv32 + off + 4));
      }
    }
    if (nt < 16) {                    // -------- Q/K: lane=token-row, regs=4 dims
      f32x4 bb = *(const f32x4*)(bqkv + nt * 16 + 4 * g);
      f32x4 acc[3] = {bb, bb, bb};    // bias as C-init
      #pragma unroll
      for (int ks = 0; ks < 4; ks++) {
        acc[0] = __builtin_amdgcn_mfma_f32_16x16x32_f16(wcur[ks], xf[0][ks], acc[0], 0,0,0);
        acc[1] = __builtin_amdgcn_mfma_f32_16x16x32_f16(wcur[ks], xf[1][ks], acc[1], 0,0,0);
        acc[2] = __builtin_amdgcn_mfma_f32_16x16x32_f16(wcur[ks], xf[2][ks], acc[2], 0,0,0);
      }
      float sc = (nt < 8) ? SCQ : 1.0f;              // Q: fold 0.25*log2e
      int col = nt * 16 + 4 * g;
      #pragma unroll
      for (int mt = 0; mt < 3; mt++) {
        f16x4 h4 = pack4z(acc[mt][0] * sc, acc[mt][1] * sc,
                          acc[mt][2] * sc, acc[mt][3] * sc);
        *(f16x4*)(smem + swz(mt * 16 + r16, col * 2)) = h4;
      }
    } else {                          // -------- V swapped: lane=dim, regs=4 rows
      float bvs = bqkv[nt * 16 + r16];
      f32x4 bb = {bvs, bvs, bvs, bvs};
      f32x4 acc[3] = {bb, bb, bb};
      #pragma unroll
      for (int ks = 0; ks < 4; ks++) {
        acc[0] = __builtin_amdgcn_mfma_f32_16x16x32_f16(xf[0][ks], wcur[ks], acc[0], 0,0,0);
        acc[1] = __builtin_amdgcn_mfma_f32_16x16x32_f16(xf[1][ks], wcur[ks], acc[1], 0,0,0);
        acc[2] = __builtin_amdgcn_mfma_f32_16x16x32_f16(xf[2][ks], wcur[ks], acc[2], 0,0,0);
      }
      int d = (nt - 16) * 16 + r16;   // vT row (dim)
      #pragma unroll
      for (int mt = 0; mt < 3; mt++) {
        #pragma unroll
        for (int p = 0; p < 2; p++) { // even rowl: pairs never straddle token edge
          int rowl = mt * 16 + 4 * g + 2 * p;
          int t = rowl >= 22;
          int col = rowl + 10 * t;    // j + 32t
          h16x2 v2 = __builtin_amdgcn_cvt_pkrtz(acc[mt][2*p], acc[mt][2*p+1]);
          *(h16x2*)(smem + vswz(d, col)) = v2;
        }
      }
    }
    #pragma unroll
    for (int ks = 0; ks < 4; ks++) wcur[ks] = wnxt[ks];
  }

  // mask regs: coalesced table loads (fallback path computes from adj)
  f32x4 mq[2][2];
  if (F16M) {
    #pragma unroll
    for (int qt = 0; qt < 2; qt++)
      #pragma unroll
      for (int jt = 0; jt < 2; jt++)
        mq[qt][jt] = *(const f32x4*)(ws + MASK_OFF + ((qt * 2 + jt) * 64 + l) * 16);
  } else {
    #pragma unroll
    for (int qt = 0; qt < 2; qt++)
      #pragma unroll
      for (int jt = 0; jt < 2; jt++)
        #pragma unroll
        for (int r = 0; r < 4; r++) {
          int q = qt * 16 + r16, j = jt * 16 + 4 * g + r;
          float m = -1e30f;
          if (j < 22) m = (q >= 22 || adj[q * 22 + j] > 0) ? 0.0f : -1e30f;
          mq[qt][jt][r] = m;
        }
  }

  // preload FIRST out-proj weight tile (latency hides under phase 2)
  f16x8 wf3a[4];
  #pragma unroll
  for (int ks = 0; ks < 4; ks++) {
    int off = (2 * wv * 16 + r16) * 128 + ks * 32 + g * 8;
    if (F16M) wf3a[ks] = *(const f16x8*)(w16o + off);
    else      wf3a[ks] = pack8z(*(const float4*)(wout32 + off),
                                *(const float4*)(wout32 + off + 4));
  }

  __syncthreads();

  // ============ Phase 2: attention (exp2 no-max softmax, deferred norm) ====
  {
    const int t = wv >> 1;
    const int rbase = 22 * t;
    const int hbase = 4 * (wv & 1);
    const int rowk0 = rbase + r16;
    int rk1 = rbase + 16 + r16; if (rk1 > 47) rk1 = 47;   // clamped (finite, masked)
    const int rowk1 = rk1;
    #pragma unroll 1                                 // ROLLED: 4 head iterations
    for (int hi = 0; hi < 4; hi++) {
      int h = hbase + hi;
      f16x4 kf0 = *(const f16x4*)(smem + swz(rowk0, (128 + h * 16 + 4 * g) * 2));
      f16x4 kf1 = *(const f16x4*)(smem + swz(rowk1, (128 + h * 16 + 4 * g) * 2));
      f16x4 vf0 = *(const f16x4*)(smem + vswz(h * 16 + r16, t * 32 + 4 * g));
      f16x4 vf1 = *(const f16x4*)(smem + vswz(h * 16 + r16, t * 32 + 16 + 4 * g));
      __builtin_amdgcn_s_setprio(1);               // T5: favor this wave's MFMA/exp cluster
      #pragma unroll
      for (int qt = 0; qt < 2; qt++) {
        int rowq = qt ? rowk1 : rowk0;
        f16x4 qf = *(const f16x4*)(smem + swz(rowq, (h * 16 + 4 * g) * 2));
        f32x4 z = {0.f, 0.f, 0.f, 0.f};
        f32x4 s0 = __builtin_amdgcn_mfma_f32_16x16x16f16(kf0, qf, z, 0, 0, 0);
        f32x4 s1 = __builtin_amdgcn_mfma_f32_16x16x16f16(kf1, qf, z, 0, 0, 0);
        float p[8];
        #pragma unroll
        for (int r = 0; r < 4; r++) {
          p[r]     = __builtin_exp2f(s0[r] + mq[qt][0][r]);  // exp2(-1e30)==0 kills mask
          p[4 + r] = __builtin_exp2f(s1[r] + mq[qt][1][r]);
        }
        float sum = ((p[0] + p[1]) + (p[2] + p[3])) + ((p[4] + p[5]) + (p[6] + p[7]));
        sum += __shfl_xor(sum, 16, 64);
        sum += __shfl_xor(sum, 32, 64);             // hides under P-pack + PV MFMA
        f16x4 pb0 = pack4z(p[0], p[1], p[2], p[3]);
        f16x4 pb1 = pack4z(p[4], p[5], p[6], p[7]);
        f32x4 ya = __builtin_amdgcn_mfma_f32_16x16x16f16(vf0, pb0, z, 0, 0, 0);
        ya = __builtin_amdgcn_mfma_f32_16x16x16f16(vf1, pb1, ya, 0, 0, 0);
        float inv = __builtin_amdgcn_rcpf(sum);
        int q = qt * 16 + r16;
        if (q < 22) {
          f16x4 yh = pack4z(ya[0] * inv, ya[1] * inv, ya[2] * inv, ya[3] * inv);
          *(f16x4*)(smem + swz(rbase + q, (h * 16 + 4 * g) * 2)) = yh;
        }
      }
      __builtin_amdgcn_s_setprio(0);
    }
  }
  __syncthreads();

  // ============ Phase 3: out projection (tile A preloaded; bias via C-init) ====
  f16x8 wf3b[4];
  #pragma unroll
  for (int ks = 0; ks < 4; ks++) {
    int off = ((2 * wv + 1) * 16 + r16) * 128 + ks * 32 + g * 8;
    if (F16M) wf3b[ks] = *(const f16x8*)(w16o + off);
    else      wf3b[ks] = pack8z(*(const float4*)(wout32 + off),
                                *(const float4*)(wout32 + off + 4));
  }
  f32x4 bva = *(const f32x4*)(bout + 2 * wv * 16 + 4 * g);
  f32x4 bvb = *(const f32x4*)(bout + (2 * wv + 1) * 16 + 4 * g);
  #pragma unroll 1                                   // ROLLED: 3 iterations
  for (int mt = 0; mt < 3; mt++) {
    f16x8 af[4];
    #pragma unroll
    for (int ks = 0; ks < 4; ks++)
      af[ks] = *(const f16x8*)(smem + swz(mt * 16 + r16, (ks * 32 + g * 8) * 2));
    int rowl = mt * 16 + r16;
    f32x4 acc0 = bva, acc1 = bvb;
    #pragma unroll
    for (int ks = 0; ks < 4; ks++) {
      acc0 = __builtin_amdgcn_mfma_f32_16x16x32_f16(wf3a[ks], af[ks], acc0, 0, 0, 0);
      acc1 = __builtin_amdgcn_mfma_f32_16x16x32_f16(wf3b[ks], af[ks], acc1, 0, 0, 0);
    }
    if (rowl < RG) {
      float4 oa, ob;
      oa.x = acc0[0]; oa.y = acc0[1]; oa.z = acc0[2]; oa.w = acc0[3];
      ob.x = acc1[0]; ob.y = acc1[1]; ob.z = acc1[2]; ob.w = acc1[3];
      *(float4*)(out + (g0 + rowl) * 128 + 2 * wv * 16 + 4 * g) = oa;
      *(float4*)(out + (g0 + rowl) * 128 + (2 * wv + 1) * 16 + 4 * g) = ob;
    }
  }
}

extern "C" void kernel_launch(void* const* d_in, const int* in_sizes, int n_in,
                              void* d_out, int out_size, void* d_ws, size_t ws_size,
                              hipStream_t stream) {
  const float* x    = (const float*)d_in[0];
  const int*   adj  = (const int*)d_in[1];
  const float* wqkv = (const float*)d_in[2];
  const float* bqkv = (const float*)d_in[3];
  const float* wout = (const float*)d_in[4];
  const float* bout = (const float*)d_in[5];
  float* o = (float*)d_out;

  int f16m = (d_ws != nullptr && ws_size >= (size_t)WS_NEEDED) ? 1 : 0;
  if (f16m) {
    prep<<<dim3(65), dim3(256), 0, stream>>>(wqkv, wout, adj, (char*)d_ws);
    mga_fused<1><<<dim3(NGROUPS), dim3(256), 0, stream>>>(
        x, adj, bqkv, bout, (const char*)d_ws, wqkv, wout, o);
  } else {
    mga_fused<0><<<dim3(NGROUPS), dim3(256), 0, stream>>>(
        x, adj, bqkv, bout, (const char*)d_ws, wqkv, wout, o);
  }
}